// Round 6
// baseline (66.102 us; speedup 1.0000x reference)
//
#include <hip/hip_runtime.h>
#include <hip/hip_bf16.h>
#include <math.h>

#define BB 16
#define CC 64
#define HW 4096
#define MM 1024
#define CK 8
#define CV 32
#define LOG2E 1.4426950408889634f

typedef float f32x4 __attribute__((ext_vector_type(4)));
typedef short s16x8 __attribute__((ext_vector_type(8)));

union U4 { uint4 u; s16x8 s; };

__device__ inline unsigned short bfu(float a) {
    __hip_bfloat16 h = __float2bfloat16(a);
    union { __hip_bfloat16 h; unsigned short u; } c; c.h = h; return c.u;
}
__device__ inline unsigned int pk2bf(float a, float b) {
    return (unsigned int)bfu(a) | ((unsigned int)bfu(b) << 16);
}

// Workspace layout (bytes):
//   fxB bf16 [b][q][8]        @ 0        (1,048,576)
//   gxA bf16 [b][k][8]        @ 1048576  (262,144)
//   hxC bf16 [b][ch][k]       @ 1310720  (1,048,576)
//   wvB bf16 tiled [4][64][8] @ 2359296  (4,096)
#define FXB_OFF 0
#define GXA_OFF 1048576
#define HXC_OFF 1310720
#define WVB_OFF 2359296

// ---------------------------------------------------------------------------
// Kernel A: per-pixel conv f/g/h with 4-way input-channel split across lane
// groups of 16 (chq = l>>4); channel combine via shfl_xor(16,32); 2x2 pool
// via shfl_xor(1,2). hxC stores staged via LDS -> coalesced.
// 1024 blocks x 256 threads -> 4 waves/SIMD.
// Wave pixel tile: 2 rows x 8 cols (16 sub-lanes s = l&15).
// ---------------------------------------------------------------------------
__global__ __launch_bounds__(256, 4) void prep_kernel(
    const float* __restrict__ x,
    const float* __restrict__ wf, const float* __restrict__ bf,
    const float* __restrict__ wg, const float* __restrict__ bg,
    const float* __restrict__ wh, const float* __restrict__ bh,
    const float* __restrict__ wv,
    unsigned short* __restrict__ fxB, unsigned short* __restrict__ gxA,
    unsigned short* __restrict__ hxC, unsigned short* __restrict__ wvB)
{
    __shared__ __align__(16) float wfs[CK * CC];
    __shared__ __align__(16) float wgs[CK * CC];
    __shared__ __align__(16) float whs[CV * CC];
    __shared__ __align__(8)  unsigned short sH[CV * 16];   // [ch][pp_local]

    int tid = threadIdx.x;
    for (int i = tid; i < CK * CC; i += 256) { wfs[i] = wf[i]; wgs[i] = wg[i]; }
    for (int i = tid; i < CV * CC; i += 256) { whs[i] = wh[i]; }

    if (blockIdx.x == 0) {
        // wv bf16 A-fragments: wvB[ot][lane][8] = wv[ot*16+(l&15)][(l>>4)*8+j]
        int t = tid >> 6, ll = tid & 63;
        const float* wr = wv + (size_t)(t * 16 + (ll & 15)) * CV + ((ll >> 4) * 8);
        uint4 wu;
        wu.x = pk2bf(wr[0], wr[1]); wu.y = pk2bf(wr[2], wr[3]);
        wu.z = pk2bf(wr[4], wr[5]); wu.w = pk2bf(wr[6], wr[7]);
        *(uint4*)(wvB + (size_t)tid * 8) = wu;
    }
    __syncthreads();

    int wavein = tid >> 6;
    int l   = tid & 63;
    int chq = l >> 4;                        // channel quarter
    int s   = l & 15;                        // pixel within tile
    int bid = blockIdx.x;
    int b     = bid >> 6;                    // 64 blocks per batch
    int t3    = bid & 63;
    int rpair = t3 >> 1;                     // pooled row, 0..31
    int chunk = t3 & 1;                      // col half
    int coff  = chunk * 4 + wavein;          // 8-col tile, 0..7
    int c = coff * 8 + ((s >> 2) & 3) * 2 + (s & 1);
    int r = rpair * 2 + ((s >> 1) & 1);
    int pix = r * 64 + c;

    float f[CK], g[CK], hh[CV];
#pragma unroll
    for (int o = 0; o < CK; ++o) { f[o] = 0.f; g[o] = 0.f; }
#pragma unroll
    for (int o = 0; o < CV; ++o) hh[o] = 0.f;

    const float* xp = x + (size_t)b * CC * HW + (size_t)chq * 16 * HW + pix;
#pragma unroll
    for (int i4 = 0; i4 < 4; ++i4) {
        int c4 = chq * 16 + i4 * 4;
        float v0 = xp[(i4 * 4 + 0) * HW];
        float v1 = xp[(i4 * 4 + 1) * HW];
        float v2 = xp[(i4 * 4 + 2) * HW];
        float v3 = xp[(i4 * 4 + 3) * HW];
#pragma unroll
        for (int o = 0; o < CK; ++o) {
            float4 w = *(const float4*)&wfs[o * CC + c4];
            f[o] = fmaf(w.x, v0, fmaf(w.y, v1, fmaf(w.z, v2, fmaf(w.w, v3, f[o]))));
        }
#pragma unroll
        for (int o = 0; o < CK; ++o) {
            float4 w = *(const float4*)&wgs[o * CC + c4];
            g[o] = fmaf(w.x, v0, fmaf(w.y, v1, fmaf(w.z, v2, fmaf(w.w, v3, g[o]))));
        }
#pragma unroll
        for (int o = 0; o < CV; ++o) {
            float4 w = *(const float4*)&whs[o * CC + c4];
            hh[o] = fmaf(w.x, v0, fmaf(w.y, v1, fmaf(w.z, v2, fmaf(w.w, v3, hh[o]))));
        }
    }

    // combine the four channel quarters (partners l^16, l^32)
#pragma unroll
    for (int o = 0; o < CK; ++o) {
        f[o] += __shfl_xor(f[o], 16, 64);
        f[o] += __shfl_xor(f[o], 32, 64);
        g[o] += __shfl_xor(g[o], 16, 64);
        g[o] += __shfl_xor(g[o], 32, 64);
    }
#pragma unroll
    for (int o = 0; o < CV; ++o) {
        hh[o] += __shfl_xor(hh[o], 16, 64);
        hh[o] += __shfl_xor(hh[o], 32, 64);
    }

    // f(x): bias + log2e scale, bf16, full-res (quarter-0 lanes write)
    if (chq == 0) {
        uint4 fu;
        fu.x = pk2bf((f[0] + bf[0]) * LOG2E, (f[1] + bf[1]) * LOG2E);
        fu.y = pk2bf((f[2] + bf[2]) * LOG2E, (f[3] + bf[3]) * LOG2E);
        fu.z = pk2bf((f[4] + bf[4]) * LOG2E, (f[5] + bf[5]) * LOG2E);
        fu.w = pk2bf((f[6] + bf[6]) * LOG2E, (f[7] + bf[7]) * LOG2E);
        *(uint4*)(fxB + (size_t)(b * HW + pix) * CK) = fu;
    }

    // 2x2 maxpool via shfl (partners s^1 = col, s^2 = row; within chq group)
#pragma unroll
    for (int o = 0; o < CK; ++o) {
        g[o] = fmaxf(g[o], __shfl_xor(g[o], 1, 64));
        g[o] = fmaxf(g[o], __shfl_xor(g[o], 2, 64));
    }
#pragma unroll
    for (int o = 0; o < CV; ++o) {
        hh[o] = fmaxf(hh[o], __shfl_xor(hh[o], 1, 64));
        hh[o] = fmaxf(hh[o], __shfl_xor(hh[o], 2, 64));
    }

    if (chq == 0 && (s & 3) == 0) {
        int pq  = s >> 2;                               // 0..3 within wave
        int ppl = wavein * 4 + pq;                      // 0..15 within block
        uint4 gu;
        gu.x = pk2bf(g[0] + bg[0], g[1] + bg[1]);
        gu.y = pk2bf(g[2] + bg[2], g[3] + bg[3]);
        gu.z = pk2bf(g[4] + bg[4], g[5] + bg[5]);
        gu.w = pk2bf(g[6] + bg[6], g[7] + bg[7]);
        *(uint4*)(gxA + (size_t)(b * MM + rpair * 32 + chunk * 16 + ppl) * CK) = gu;
#pragma unroll
        for (int o = 0; o < CV; ++o)
            sH[o * 16 + ppl] = bfu(hh[o] + bh[o]);
    }
    __syncthreads();

    // coalesced hxC store: 32 ch x 16 pooled pixels, 4 B per thread (2 bf16)
    {
        int ch = tid >> 3, part = tid & 7;              // 32 x 8
        unsigned int v = *(const unsigned int*)&sH[ch * 16 + part * 2];
        *(unsigned int*)(hxC + (size_t)(b * CV + ch) * MM
                         + rpair * 32 + chunk * 16 + part * 2) = v;
    }
}

// ---------------------------------------------------------------------------
// Kernel B: MFMA flash attention. One wave = ONE 16-query tile x all 1024
// keys; no LDS, no barriers, no cross-wave combine. 1024 blocks x 4 waves
// -> 4096 waves; launch_bounds(256,6) targets 6 waves/SIMD.
// Key->row permutation perm(rho)=((rho&12)<<1)|(rho&3) makes the exp'd S^T
// fragment directly usable as the PV B-fragment with zero cross-lane ops.
// ---------------------------------------------------------------------------
__global__ __launch_bounds__(256, 6) void attn_kernel(
    const float* __restrict__ x,
    const unsigned short* __restrict__ fxB, const unsigned short* __restrict__ gxA,
    const unsigned short* __restrict__ hxC, const unsigned short* __restrict__ wvB,
    const float* __restrict__ bv, const float* __restrict__ gamma,
    float* __restrict__ out)
{
    int tid = threadIdx.x;
    int l   = tid & 63;
    int w   = tid >> 6;
    int b   = blockIdx.x >> 6;                  // 64 blocks per batch
    int qb  = (blockIdx.x & 63) * 64 + w * 16;  // wave's query base
    int q16 = l & 15;
    int h   = l >> 4;
    int prm = ((q16 & 12) << 1) | (q16 & 3);    // permuted row offset
    bool lo16 = (l < 16);

    // Q fragment (B-operand): lane holds fx[qb+(l&15)][ch 0..7] if l<16
    U4 qf;
    {
        uint4 v = *(const uint4*)(fxB + (size_t)(b * HW + qb + q16) * CK);
        if (!lo16) { v.x = 0; v.y = 0; v.z = 0; v.w = 0; }
        qf.u = v;
    }

    f32x4 zz = {0.f, 0.f, 0.f, 0.f};
    f32x4 acc0 = zz, acc1 = zz;
    float ssum = 0.f;

    const unsigned short* gxb = gxA + (size_t)b * MM * CK;
    const unsigned short* hxb = hxC + (size_t)b * CV * MM;

#pragma unroll 2
    for (int g = 0; g < 32; ++g) {
        // gx A-fragments; lanes>=16 duplicate rows but hit Q-side zeros (k>=8)
        U4 ga, gb2;
        ga.u  = *(const uint4*)(gxb + (size_t)(g * 32 + prm) * CK);
        gb2.u = *(const uint4*)(gxb + (size_t)(g * 32 + prm + 4) * CK);
        // V A-fragments: row rho -> phys ch perm(rho)(+4); cols keys g*32+8h..+7
        U4 v0, v1;
        v0.u = *(const uint4*)(hxb + (size_t)(prm)     * MM + g * 32 + h * 8);
        v1.u = *(const uint4*)(hxb + (size_t)(prm + 4) * MM + g * 32 + h * 8);

        f32x4 s0 = __builtin_amdgcn_mfma_f32_16x16x32_bf16(ga.s,  qf.s, zz, 0, 0, 0);
        f32x4 s1 = __builtin_amdgcn_mfma_f32_16x16x32_bf16(gb2.s, qf.s, zz, 0, 0, 0);
        // shift-free softmax: scores bounded; fx pre-scaled by log2e
        float e0 = __builtin_exp2f(s0.x), e1 = __builtin_exp2f(s0.y);
        float e2 = __builtin_exp2f(s0.z), e3 = __builtin_exp2f(s0.w);
        float e4 = __builtin_exp2f(s1.x), e5 = __builtin_exp2f(s1.y);
        float e6 = __builtin_exp2f(s1.z), e7 = __builtin_exp2f(s1.w);
        ssum += ((e0 + e1) + (e2 + e3)) + ((e4 + e5) + (e6 + e7));
        U4 bp;
        bp.u.x = pk2bf(e0, e1); bp.u.y = pk2bf(e2, e3);
        bp.u.z = pk2bf(e4, e5); bp.u.w = pk2bf(e6, e7);
        acc0 = __builtin_amdgcn_mfma_f32_16x16x32_bf16(v0.s, bp.s, acc0, 0, 0, 0);
        acc1 = __builtin_amdgcn_mfma_f32_16x16x32_bf16(v1.s, bp.s, acc1, 0, 0, 0);
    }

    // softmax denominator across the 4 h-groups
    float cs = ssum;
    cs += __shfl_xor(cs, 16, 64);
    cs += __shfl_xor(cs, 32, 64);
    float inv = 1.0f / cs;

    float gm = gamma[0];
    U4 wva[4];
#pragma unroll
    for (int ot = 0; ot < 4; ++ot)
        wva[ot].u = *(const uint4*)(wvB + (size_t)(ot * 64 + l) * CK);

    U4 mb;
    mb.u.x = pk2bf(acc0.x * inv, acc0.y * inv);
    mb.u.y = pk2bf(acc0.z * inv, acc0.w * inv);
    mb.u.z = pk2bf(acc1.x * inv, acc1.y * inv);
    mb.u.w = pk2bf(acc1.z * inv, acc1.w * inv);

    int q = qb + q16;
    const float* xq = x + (size_t)b * CC * HW + q;
    float*       oq = out + (size_t)b * CC * HW + q;
#pragma unroll
    for (int ot = 0; ot < 4; ++ot) {
        f32x4 d = __builtin_amdgcn_mfma_f32_16x16x32_bf16(wva[ot].s, mb.s, zz, 0, 0, 0);
#pragma unroll
        for (int r = 0; r < 4; ++r) {
            int o = ot * 16 + h * 4 + r;
            oq[(size_t)o * HW] = xq[(size_t)o * HW] + gm * (d[r] + bv[o]);
        }
    }
}

extern "C" void kernel_launch(void* const* d_in, const int* in_sizes, int n_in,
                              void* d_out, int out_size, void* d_ws, size_t ws_size,
                              hipStream_t stream) {
    const float* x     = (const float*)d_in[0];
    const float* wf    = (const float*)d_in[1];
    const float* bf    = (const float*)d_in[2];
    const float* wg    = (const float*)d_in[3];
    const float* bg    = (const float*)d_in[4];
    const float* wh    = (const float*)d_in[5];
    const float* bh    = (const float*)d_in[6];
    const float* wv    = (const float*)d_in[7];
    const float* bv    = (const float*)d_in[8];
    const float* gamma = (const float*)d_in[9];
    float* out = (float*)d_out;
    char* ws = (char*)d_ws;

    unsigned short* fxB = (unsigned short*)(ws + FXB_OFF);
    unsigned short* gxA = (unsigned short*)(ws + GXA_OFF);
    unsigned short* hxC = (unsigned short*)(ws + HXC_OFF);
    unsigned short* wvB = (unsigned short*)(ws + WVB_OFF);

    // Kernel A: 262144 threads (4-way channel split), 1024 blocks
    prep_kernel<<<1024, 256, 0, stream>>>(x, wf, bf, wg, bg, wh, bh, wv,
                                          fxB, gxA, hxC, wvB);
    // Kernel B: 1024 blocks x 4 waves; wave = 16 queries x 1024 keys
    attn_kernel<<<1024, 256, 0, stream>>>(x, fxB, gxA, hxC, wvB, bv, gamma, out);
}